// Round 1
// baseline (739.437 us; speedup 1.0000x reference)
//
#include <hip/hip_runtime.h>
#include <cstddef>

// NonLocal block, MI355X. Round 1: correct fp32 baseline, fused softmax
// (never materializes the 8x4096x4096 attention matrix).
//
// Math: attn[n,m] = 2^(c2[n,m] + g2[n]),  c2 = (y2.y1)*log2e (log2e folded
// into stored y2), g2[n] = -log2(sum_m 2^c2[n,m]).  c2 max ~ 20 << 127 so no
// max-subtraction needed (single v_exp_f32 per score, no serial max chain).

namespace {
constexpr int kB   = 8;
constexpr int kC   = 256;
constexpr int kCi  = 32;
constexpr int kN   = 4096;           // H*W
constexpr int kRows = kB * kN;       // 32768
constexpr int kMCH = 8;              // m-chunks for the stats pass
constexpr float kLog2e = 1.4426950408889634f;
}

__device__ __forceinline__ float fast_exp2(float x) { return __builtin_amdgcn_exp2f(x); }
__device__ __forceinline__ float fast_rcp(float x)  { return __builtin_amdgcn_rcpf(x); }
__device__ __forceinline__ float fast_log2(float x) { return __builtin_amdgcn_logf(x); }
__device__ __forceinline__ float silu(float t) {
    return t * fast_rcp(1.f + fast_exp2(-t * kLog2e));
}

// ---------------------------------------------------------------------------
// K1: the three 1x1 conv + BN + SiLU projections.
// Block = 256 threads = 4 waves; block owns a 64-pixel tile; wave ig owns 24
// of the 96 output channels. x tile staged in LDS [256c][64px]; weight reads
// are wave-uniform -> s_load + v_fmac with SGPR operand.
// Outputs stored transposed [b][n][32]; y2 is pre-scaled by log2e.
// ---------------------------------------------------------------------------
__global__ __launch_bounds__(256) void k1_proj(
    const float* __restrict__ x,
    const float* __restrict__ w1, const float* __restrict__ s1, const float* __restrict__ b1,
    const float* __restrict__ w2, const float* __restrict__ s2, const float* __restrict__ b2,
    const float* __restrict__ w3, const float* __restrict__ s3, const float* __restrict__ b3,
    float* __restrict__ y1t, float* __restrict__ y2t, float* __restrict__ y3t)
{
    __shared__ float xs[kC][64];
    const int t   = threadIdx.x;
    const int gp0 = blockIdx.x * 64;          // first pixel of this tile
    const int b   = gp0 >> 12;
    const int n0  = gp0 & (kN - 1);

    const float* xb = x + (size_t)b * kC * kN + n0;
    #pragma unroll 4
    for (int it = 0; it < 64; ++it) {
        int idx = it * 256 + t;
        int c   = idx >> 6;
        int px  = idx & 63;
        xs[c][px] = xb[(size_t)c * kN + px];  // 64 consecutive floats per wave
    }
    __syncthreads();

    const int ig  = __builtin_amdgcn_readfirstlane(t >> 6);  // wave id 0..3
    const int px  = t & 63;
    const int gi0 = ig * 24;

    const float* rowp[24];
    #pragma unroll
    for (int j = 0; j < 24; ++j) {
        int gi = gi0 + j;
        const float* w = (gi < 32) ? w1 : (gi < 64) ? w2 : w3;
        rowp[j] = w + (size_t)(gi & 31) * kC;
    }

    float acc[24];
    #pragma unroll
    for (int j = 0; j < 24; ++j) acc[j] = 0.f;

    for (int c = 0; c < kC; c += 4) {
        float x0 = xs[c + 0][px];
        float x1 = xs[c + 1][px];
        float x2 = xs[c + 2][px];
        float x3 = xs[c + 3][px];
        #pragma unroll
        for (int j = 0; j < 24; ++j) {
            acc[j] = fmaf(rowp[j][c + 0], x0, acc[j]);
            acc[j] = fmaf(rowp[j][c + 1], x1, acc[j]);
            acc[j] = fmaf(rowp[j][c + 2], x2, acc[j]);
            acc[j] = fmaf(rowp[j][c + 3], x3, acc[j]);
        }
    }

    const size_t row = ((size_t)b * kN + n0 + px) * kCi;
    #pragma unroll
    for (int j = 0; j < 24; ++j) {
        int gi = gi0 + j;
        int ii = gi & 31;
        const float* ss; const float* bb; float* dst; float mul;
        if (gi < 32)      { ss = s1; bb = b1; dst = y1t + row + ii; mul = 1.f; }
        else if (gi < 64) { ss = s2; bb = b2; dst = y2t + row + ii; mul = kLog2e; }
        else              { ss = s3; bb = b3; dst = y3t + row + ii; mul = 1.f; }
        float tt = fmaf(acc[j], ss[ii], bb[ii]);
        *dst = silu(tt) * mul;
    }
}

// ---------------------------------------------------------------------------
// K2: row sums of 2^c2 (softmax denominators), chunked over m for occupancy.
// Thread owns one row n; y1 rows are wave-uniform -> scalar loads.
// ---------------------------------------------------------------------------
__global__ __launch_bounds__(256) void k2_stats(
    const float* __restrict__ y1t, const float* __restrict__ y2t,
    float* __restrict__ psum, int mlen)
{
    const int p  = blockIdx.x * 256 + threadIdx.x;                  // row id
    const int b  = __builtin_amdgcn_readfirstlane(blockIdx.x >> 4); // 16 blocks/batch
    const int m0 = blockIdx.y * mlen;

    float a[kCi];
    const float* ar = y2t + (size_t)p * kCi;
    #pragma unroll
    for (int k = 0; k < kCi; k += 4) {
        float4 v = *reinterpret_cast<const float4*>(ar + k);
        a[k] = v.x; a[k + 1] = v.y; a[k + 2] = v.z; a[k + 3] = v.w;
    }

    const float* y1b = y1t + ((size_t)b * kN + m0) * kCi;
    float l0 = 0.f, l1 = 0.f;
    for (int m = 0; m < mlen; m += 2) {
        const float* r0 = y1b + (size_t)m * kCi;
        const float* r1 = r0 + kCi;
        float d0 = 0, d1 = 0, d2 = 0, d3 = 0;
        float e0 = 0, e1 = 0, e2 = 0, e3 = 0;
        #pragma unroll
        for (int k = 0; k < kCi; k += 4) {
            d0 = fmaf(a[k + 0], r0[k + 0], d0);
            d1 = fmaf(a[k + 1], r0[k + 1], d1);
            d2 = fmaf(a[k + 2], r0[k + 2], d2);
            d3 = fmaf(a[k + 3], r0[k + 3], d3);
            e0 = fmaf(a[k + 0], r1[k + 0], e0);
            e1 = fmaf(a[k + 1], r1[k + 1], e1);
            e2 = fmaf(a[k + 2], r1[k + 2], e2);
            e3 = fmaf(a[k + 3], r1[k + 3], e3);
        }
        l0 += fast_exp2((d0 + d1) + (d2 + d3));
        l1 += fast_exp2((e0 + e1) + (e2 + e3));
    }
    psum[(size_t)blockIdx.y * kRows + p] = l0 + l1;
}

__global__ __launch_bounds__(256) void k2_reduce(
    const float* __restrict__ psum, float* __restrict__ g2)
{
    int p = blockIdx.x * 256 + threadIdx.x;
    float l = 0.f;
    #pragma unroll
    for (int ch = 0; ch < kMCH; ++ch) l += psum[(size_t)ch * kRows + p];
    g2[p] = -fast_log2(l);
}

// ---------------------------------------------------------------------------
// K3: y_last[c,m] = sum_n 2^(c2[n,m]+g2[n]) * y3[n][c], chunked over n.
// Thread owns one output column m (a[] = y1 row m); y2/y3 rows wave-uniform.
// ---------------------------------------------------------------------------
__global__ __launch_bounds__(256) void k3_pv(
    const float* __restrict__ y1t, const float* __restrict__ y2t,
    const float* __restrict__ y3t, const float* __restrict__ g2,
    float* __restrict__ pacc, int nlen)
{
    const int p  = blockIdx.x * 256 + threadIdx.x;                  // column id
    const int b  = __builtin_amdgcn_readfirstlane(blockIdx.x >> 4);
    const int n0 = blockIdx.y * nlen;

    float a[kCi];
    const float* ar = y1t + (size_t)p * kCi;
    #pragma unroll
    for (int k = 0; k < kCi; k += 4) {
        float4 v = *reinterpret_cast<const float4*>(ar + k);
        a[k] = v.x; a[k + 1] = v.y; a[k + 2] = v.z; a[k + 3] = v.w;
    }

    float acc[kCi];
    #pragma unroll
    for (int k = 0; k < kCi; ++k) acc[k] = 0.f;

    const float* y2b = y2t + ((size_t)b * kN + n0) * kCi;
    const float* y3b = y3t + ((size_t)b * kN + n0) * kCi;
    const float* gb  = g2 + (size_t)b * kN + n0;

    for (int n = 0; n < nlen; ++n) {
        const float* r2 = y2b + (size_t)n * kCi;
        float d0 = 0, d1 = 0, d2 = 0, d3 = 0;
        #pragma unroll
        for (int k = 0; k < kCi; k += 4) {
            d0 = fmaf(a[k + 0], r2[k + 0], d0);
            d1 = fmaf(a[k + 1], r2[k + 1], d1);
            d2 = fmaf(a[k + 2], r2[k + 2], d2);
            d3 = fmaf(a[k + 3], r2[k + 3], d3);
        }
        float pw = fast_exp2(((d0 + d1) + (d2 + d3)) + gb[n]);
        const float* r3 = y3b + (size_t)n * kCi;
        #pragma unroll
        for (int k = 0; k < kCi; ++k) acc[k] = fmaf(pw, r3[k], acc[k]);
    }

    float* dst = pacc + ((size_t)blockIdx.y * kRows + p) * kCi;
    #pragma unroll
    for (int k = 0; k < kCi; k += 4) {
        *reinterpret_cast<float4*>(dst + k) =
            make_float4(acc[k], acc[k + 1], acc[k + 2], acc[k + 3]);
    }
}

__global__ __launch_bounds__(256) void k3_reduce(
    const float* __restrict__ pacc, float* __restrict__ ylt, int nch)
{
    size_t i = (size_t)blockIdx.x * 256 + threadIdx.x;   // float4 index
    const float4* src = reinterpret_cast<const float4*>(pacc);
    float4 s = src[i];
    for (int ch = 1; ch < nch; ++ch) {
        float4 v = src[(size_t)ch * ((size_t)kRows * kCi / 4) + i];
        s.x += v.x; s.y += v.y; s.z += v.z; s.w += v.w;
    }
    reinterpret_cast<float4*>(ylt)[i] = s;
}

// ---------------------------------------------------------------------------
// K4: final 1x1 conv (32 -> 256) + BN + SiLU + residual.
// Thread owns one pixel; grid.y covers the 256 outputs in 8 chunks of 32.
// ---------------------------------------------------------------------------
__global__ __launch_bounds__(256) void k4_out(
    const float* __restrict__ ylt, const float* __restrict__ w4,
    const float* __restrict__ s4, const float* __restrict__ b4,
    const float* __restrict__ x, float* __restrict__ out)
{
    const int gp = blockIdx.x * 256 + threadIdx.x;   // pixel id
    const int b  = __builtin_amdgcn_readfirstlane(blockIdx.x >> 4);
    const int n  = gp & (kN - 1);
    const int o0 = blockIdx.y * 32;

    float yv[kCi];
    const float* yr = ylt + (size_t)gp * kCi;
    #pragma unroll
    for (int k = 0; k < kCi; k += 4) {
        float4 v = *reinterpret_cast<const float4*>(yr + k);
        yv[k] = v.x; yv[k + 1] = v.y; yv[k + 2] = v.z; yv[k + 3] = v.w;
    }

    const size_t base = ((size_t)b * kC + o0) * kN + n;
    #pragma unroll 4
    for (int o = 0; o < 32; ++o) {
        const float* wr = w4 + (size_t)(o0 + o) * kCi;
        float d0 = 0, d1 = 0, d2 = 0, d3 = 0;
        #pragma unroll
        for (int k = 0; k < kCi; k += 4) {
            d0 = fmaf(wr[k + 0], yv[k + 0], d0);
            d1 = fmaf(wr[k + 1], yv[k + 1], d1);
            d2 = fmaf(wr[k + 2], yv[k + 2], d2);
            d3 = fmaf(wr[k + 3], yv[k + 3], d3);
        }
        float tt = fmaf((d0 + d1) + (d2 + d3), s4[o0 + o], b4[o0 + o]);
        out[base + (size_t)o * kN] = silu(tt) + x[base + (size_t)o * kN];
    }
}

// ---------------------------------------------------------------------------
extern "C" void kernel_launch(void* const* d_in, const int* in_sizes, int n_in,
                              void* d_out, int out_size, void* d_ws, size_t ws_size,
                              hipStream_t stream)
{
    (void)in_sizes; (void)n_in; (void)out_size;
    const float* x  = (const float*)d_in[0];
    const float* w1 = (const float*)d_in[1];
    const float* s1 = (const float*)d_in[2];
    const float* b1 = (const float*)d_in[3];
    const float* w2 = (const float*)d_in[4];
    const float* s2 = (const float*)d_in[5];
    const float* b2 = (const float*)d_in[6];
    const float* w3 = (const float*)d_in[7];
    const float* s3 = (const float*)d_in[8];
    const float* b3 = (const float*)d_in[9];
    const float* w4 = (const float*)d_in[10];
    const float* s4 = (const float*)d_in[11];
    const float* b4 = (const float*)d_in[12];
    float* out = (float*)d_out;

    float* ws = (float*)d_ws;
    size_t off = 0;
    float* y1t = ws + off; off += (size_t)kRows * kCi;   // [b][n][32]
    float* y2t = ws + off; off += (size_t)kRows * kCi;   // pre-scaled by log2e
    float* y3t = ws + off; off += (size_t)kRows * kCi;
    float* g2  = ws + off; off += (size_t)kRows;
    float* psum= ws + off; off += (size_t)kMCH * kRows;
    float* ylt = ws + off; off += (size_t)kRows * kCi;

    // n-chunk count for K3, shrunk if the workspace is small.
    int nch = 8;
    while (nch > 1 &&
           (off + (size_t)nch * kRows * kCi) * sizeof(float) > ws_size) nch >>= 1;
    float* pacc = ws + off;

    k1_proj<<<dim3(kRows / 64), dim3(256), 0, stream>>>(
        x, w1, s1, b1, w2, s2, b2, w3, s3, b3, y1t, y2t, y3t);
    k2_stats<<<dim3(kRows / 256, kMCH), dim3(256), 0, stream>>>(
        y1t, y2t, psum, kN / kMCH);
    k2_reduce<<<dim3(kRows / 256), dim3(256), 0, stream>>>(psum, g2);
    k3_pv<<<dim3(kRows / 256, nch), dim3(256), 0, stream>>>(
        y1t, y2t, y3t, g2, pacc, kN / nch);
    k3_reduce<<<dim3((kRows * kCi / 4) / 256), dim3(256), 0, stream>>>(
        pacc, ylt, nch);
    k4_out<<<dim3(kRows / 256, kC / 32), dim3(256), 0, stream>>>(
        ylt, w4, s4, b4, x, out);
}

// Round 2
// 340.238 us; speedup vs baseline: 2.1733x; 2.1733x over previous
//
#include <hip/hip_runtime.h>
#include <hip/hip_bf16.h>
#include <cstddef>
#include <cstdint>

// NonLocal block, MI355X. Round 2: attention passes on MFMA (bf16), fused
// softmax with NO per-row bias in the hot loop:
//   out[m] = sum_n 2^S[n,m] * v3[n],  v3[n] = y3[n] / sum_m 2^S[n,m]
// (S = c*log2e via y2 pre-scale; S+g2 <= 0 so 2^S * v3 never overflows.)

namespace {
constexpr int kBt  = 8;
constexpr int kC   = 256;
constexpr int kCi  = 32;
constexpr int kN   = 4096;           // H*W
constexpr int kRowsT = kBt * kN;     // 32768
constexpr float kLog2e = 1.4426950408889634f;

typedef __attribute__((ext_vector_type(8))) short short8;
typedef __attribute__((ext_vector_type(4))) float f32x4;
}

__device__ __forceinline__ float fast_exp2(float x) { return __builtin_amdgcn_exp2f(x); }
__device__ __forceinline__ float fast_rcp(float x)  { return __builtin_amdgcn_rcpf(x); }
__device__ __forceinline__ float silu(float t) {
    return t * fast_rcp(1.f + fast_exp2(-t * kLog2e));
}
__device__ __forceinline__ unsigned short f2bf(float f) {
    union { float f; uint32_t u; } v; v.f = f;
    return (unsigned short)((v.u + 0x7FFFu + ((v.u >> 16) & 1u)) >> 16);
}
__device__ __forceinline__ float bf2f(unsigned short u) {
    union { uint32_t u; float f; } v; v.u = ((uint32_t)u) << 16;
    return v.f;
}

// ---------------------------------------------------------------------------
// K1: three 1x1 conv + BN + SiLU projections -> bf16 rows [b*n][32].
// y2 is pre-scaled by log2e.
// ---------------------------------------------------------------------------
__global__ __launch_bounds__(256) void k1_proj(
    const float* __restrict__ x,
    const float* __restrict__ w1, const float* __restrict__ s1, const float* __restrict__ b1,
    const float* __restrict__ w2, const float* __restrict__ s2, const float* __restrict__ b2,
    const float* __restrict__ w3, const float* __restrict__ s3, const float* __restrict__ b3,
    unsigned short* __restrict__ y1t, unsigned short* __restrict__ y2t,
    unsigned short* __restrict__ y3t)
{
    __shared__ float xs[kC][64];
    const int t   = threadIdx.x;
    const int gp0 = blockIdx.x * 64;
    const int b   = gp0 >> 12;
    const int n0  = gp0 & (kN - 1);

    const float* xb = x + (size_t)b * kC * kN + n0;
    #pragma unroll 4
    for (int it = 0; it < 64; ++it) {
        int idx = it * 256 + t;
        int c   = idx >> 6;
        int px  = idx & 63;
        xs[c][px] = xb[(size_t)c * kN + px];
    }
    __syncthreads();

    const int ig  = __builtin_amdgcn_readfirstlane(t >> 6);
    const int px  = t & 63;
    const int gi0 = ig * 24;

    const float* rowp[24];
    #pragma unroll
    for (int j = 0; j < 24; ++j) {
        int gi = gi0 + j;
        const float* w = (gi < 32) ? w1 : (gi < 64) ? w2 : w3;
        rowp[j] = w + (size_t)(gi & 31) * kC;
    }

    float acc[24];
    #pragma unroll
    for (int j = 0; j < 24; ++j) acc[j] = 0.f;

    for (int c = 0; c < kC; c += 4) {
        float x0 = xs[c + 0][px];
        float x1 = xs[c + 1][px];
        float x2 = xs[c + 2][px];
        float x3 = xs[c + 3][px];
        #pragma unroll
        for (int j = 0; j < 24; ++j) {
            acc[j] = fmaf(rowp[j][c + 0], x0, acc[j]);
            acc[j] = fmaf(rowp[j][c + 1], x1, acc[j]);
            acc[j] = fmaf(rowp[j][c + 2], x2, acc[j]);
            acc[j] = fmaf(rowp[j][c + 3], x3, acc[j]);
        }
    }

    const size_t row = ((size_t)b * kN + n0 + px) * kCi;
    #pragma unroll
    for (int j = 0; j < 24; ++j) {
        int gi = gi0 + j;
        int ii = gi & 31;
        const float* ss; const float* bb; unsigned short* dst; float mul;
        if (gi < 32)      { ss = s1; bb = b1; dst = y1t + row + ii; mul = 1.f; }
        else if (gi < 64) { ss = s2; bb = b2; dst = y2t + row + ii; mul = kLog2e; }
        else              { ss = s3; bb = b3; dst = y3t + row + ii; mul = 1.f; }
        float tt = fmaf(acc[j], ss[ii], bb[ii]);
        *dst = f2bf(silu(tt) * mul);
    }
}

// ---------------------------------------------------------------------------
// KA: softmax denominators via MFMA, then v3T[b][c][n] = y3[n][c]/sumexp[n].
// Block = 4 waves, 64 n-rows (wave owns 16); loop m in 16-col steps.
// S tile D-layout: lane l -> col m = l&15, row n = 4*(l>>4)+r.
// ---------------------------------------------------------------------------
__global__ __launch_bounds__(256) void kA_stats(
    const unsigned short* __restrict__ y1t, const unsigned short* __restrict__ y2t,
    const unsigned short* __restrict__ y3t, unsigned short* __restrict__ v3T)
{
    const int l   = threadIdx.x & 63;
    const int w   = __builtin_amdgcn_readfirstlane(threadIdx.x >> 6);
    const int b   = blockIdx.x >> 6;
    const int n0  = (blockIdx.x & 63) * 64;
    const int r16 = l & 15, g = l >> 4;

    // A fragment: y2 rows n0 + w*16 + (l&15), k = channels (l>>4)*8 .. +7
    const short8 Af = *(const short8*)(
        y2t + ((size_t)(b * kN + n0 + w * 16 + r16) * kCi + g * 8));
    const unsigned short* y1b = y1t + (size_t)b * kN * kCi + (size_t)r16 * kCi + g * 8;

    float s0 = 0.f, s1 = 0.f, s2 = 0.f, s3 = 0.f;
    #pragma unroll 4
    for (int mt = 0; mt < kN / 16; ++mt) {
        short8 Bf = *(const short8*)(y1b + (size_t)mt * 16 * kCi);
        f32x4 z = {0.f, 0.f, 0.f, 0.f};
        f32x4 S = __builtin_amdgcn_mfma_f32_16x16x32_bf16(Af, Bf, z, 0, 0, 0);
        s0 += fast_exp2(S[0]);
        s1 += fast_exp2(S[1]);
        s2 += fast_exp2(S[2]);
        s3 += fast_exp2(S[3]);
    }
    // reduce over the 16 lanes of each group (they hold the same 4 n, all m)
    #pragma unroll
    for (int d = 1; d < 16; d <<= 1) {
        s0 += __shfl_xor(s0, d);
        s1 += __shfl_xor(s1, d);
        s2 += __shfl_xor(s2, d);
        s3 += __shfl_xor(s3, d);
    }
    __shared__ float ssum[64];
    if (r16 == 0) {
        ssum[w * 16 + g * 4 + 0] = s0;
        ssum[w * 16 + g * 4 + 1] = s1;
        ssum[w * 16 + g * 4 + 2] = s2;
        ssum[w * 16 + g * 4 + 3] = s3;
    }
    __syncthreads();

    // v3T transpose-write: thread t -> channel c = t>>3, n-span q*8..q*8+7
    const int t = threadIdx.x;
    const int c = t >> 3, q = t & 7;
    float rin[8];
    #pragma unroll
    for (int u = 0; u < 8; ++u) rin[u] = fast_rcp(ssum[q * 8 + u]);
    unsigned int wds[4];
    #pragma unroll
    for (int u = 0; u < 4; ++u) {
        float a0 = bf2f(y3t[(size_t)(b * kN + n0 + q * 8 + 2 * u) * kCi + c]) * rin[2 * u];
        float a1 = bf2f(y3t[(size_t)(b * kN + n0 + q * 8 + 2 * u + 1) * kCi + c]) * rin[2 * u + 1];
        wds[u] = (unsigned)f2bf(a0) | ((unsigned)f2bf(a1) << 16);
    }
    uint4 pack = make_uint4(wds[0], wds[1], wds[2], wds[3]);
    *(uint4*)(v3T + ((size_t)(b * kCi + c) * kN + n0 + q * 8)) = pack;
}

// ---------------------------------------------------------------------------
// KB: out[m][c] = sum_n 2^S[n,m] * v3[n][c], MFMA both matmuls.
// Block = 4 waves, 64 m-cols (wave owns 16); loop n in 32-chunks.
// P goes D-layout -> bf16 -> per-wave LDS tile [16 m][32 n] (80B row) ->
// ds_read_b128 as the PV B-fragment. A = v3T rows (contiguous 16B loads).
// ---------------------------------------------------------------------------
__global__ __launch_bounds__(256) void kB_pv(
    const unsigned short* __restrict__ y1t, const unsigned short* __restrict__ y2t,
    const unsigned short* __restrict__ v3T, float* __restrict__ ylt)
{
    __shared__ unsigned int plds[4][20 * 16];   // per-wave P tile, 80B row stride
    const int l   = threadIdx.x & 63;
    const int w   = __builtin_amdgcn_readfirstlane(threadIdx.x >> 6);
    const int b   = blockIdx.x >> 6;
    const int m0  = (blockIdx.x & 63) * 64 + w * 16;
    const int r16 = l & 15, g = l >> 4;

    // B1 fragment: y1 rows m0 + (l&15) as MFMA B-cols, k = channels
    const short8 B1 = *(const short8*)(
        y1t + ((size_t)(b * kN + m0 + r16) * kCi + g * 8));
    const unsigned short* y2b = y2t + (size_t)b * kN * kCi + (size_t)r16 * kCi + g * 8;
    const unsigned short* v3b = v3T + (size_t)b * kCi * kN + (size_t)r16 * kN + g * 8;

    f32x4 acc0 = {0.f, 0.f, 0.f, 0.f};
    f32x4 acc1 = {0.f, 0.f, 0.f, 0.f};
    unsigned int* pw = &plds[w][r16 * 20];

    #pragma unroll 2
    for (int nt = 0; nt < kN / 32; ++nt) {
        const size_t nb = (size_t)nt * 32;
        short8 A2a = *(const short8*)(y2b + nb * kCi);
        short8 A2b = *(const short8*)(y2b + (nb + 16) * kCi);
        f32x4 z = {0.f, 0.f, 0.f, 0.f};
        f32x4 S0 = __builtin_amdgcn_mfma_f32_16x16x32_bf16(A2a, B1, z, 0, 0, 0);
        f32x4 S1 = __builtin_amdgcn_mfma_f32_16x16x32_bf16(A2b, B1, z, 0, 0, 0);

        float p0 = fast_exp2(S0[0]), p1 = fast_exp2(S0[1]);
        float p2 = fast_exp2(S0[2]), p3 = fast_exp2(S0[3]);
        float p4 = fast_exp2(S1[0]), p5 = fast_exp2(S1[1]);
        float p6 = fast_exp2(S1[2]), p7 = fast_exp2(S1[3]);

        // lane's S values live at n-local = 4g+r (tile0) / 16+4g+r (tile1),
        // m-local = l&15.  Store m-major so the B-frag read is one b128.
        uint2 w01, w23;
        w01.x = (unsigned)f2bf(p0) | ((unsigned)f2bf(p1) << 16);
        w01.y = (unsigned)f2bf(p2) | ((unsigned)f2bf(p3) << 16);
        w23.x = (unsigned)f2bf(p4) | ((unsigned)f2bf(p5) << 16);
        w23.y = (unsigned)f2bf(p6) | ((unsigned)f2bf(p7) << 16);
        *(uint2*)(pw + 2 * g)     = w01;   // n-local 4g..4g+3
        *(uint2*)(pw + 8 + 2 * g) = w23;   // n-local 16+4g..+3

        short8 A3a = *(const short8*)(v3b + nb);            // c rows 0..15
        short8 A3b = *(const short8*)(v3b + 16 * (size_t)kN + nb);  // c 16..31

        asm volatile("" ::: "memory");  // keep ds_read after ds_writes
        short8 Bp = *(const short8*)(&plds[w][r16 * 20 + 4 * g]);  // k = n 8g..8g+7

        acc0 = __builtin_amdgcn_mfma_f32_16x16x32_bf16(A3a, Bp, acc0, 0, 0, 0);
        acc1 = __builtin_amdgcn_mfma_f32_16x16x32_bf16(A3b, Bp, acc1, 0, 0, 0);
    }

    // D layout: lane -> m = l&15, c = 4g+r (acc0) / 16+4g+r (acc1)
    float* outp = ylt + (size_t)(b * kN + m0 + r16) * kCi + 4 * g;
    *(float4*)(outp)      = make_float4(acc0[0], acc0[1], acc0[2], acc0[3]);
    *(float4*)(outp + 16) = make_float4(acc1[0], acc1[1], acc1[2], acc1[3]);
}

// ---------------------------------------------------------------------------
// K4: final 1x1 conv (32 -> 256) + BN + SiLU + residual.
// ---------------------------------------------------------------------------
__global__ __launch_bounds__(256) void k4_out(
    const float* __restrict__ ylt, const float* __restrict__ w4,
    const float* __restrict__ s4, const float* __restrict__ b4,
    const float* __restrict__ x, float* __restrict__ out)
{
    const int gp = blockIdx.x * 256 + threadIdx.x;
    const int b  = __builtin_amdgcn_readfirstlane(blockIdx.x >> 4);
    const int n  = gp & (kN - 1);
    const int o0 = blockIdx.y * 32;

    float yv[kCi];
    const float* yr = ylt + (size_t)gp * kCi;
    #pragma unroll
    for (int k = 0; k < kCi; k += 4) {
        float4 v = *reinterpret_cast<const float4*>(yr + k);
        yv[k] = v.x; yv[k + 1] = v.y; yv[k + 2] = v.z; yv[k + 3] = v.w;
    }

    const size_t base = ((size_t)b * kC + o0) * kN + n;
    #pragma unroll 4
    for (int o = 0; o < 32; ++o) {
        const float* wr = w4 + (size_t)(o0 + o) * kCi;
        float d0 = 0, d1 = 0, d2 = 0, d3 = 0;
        #pragma unroll
        for (int k = 0; k < kCi; k += 4) {
            d0 = fmaf(wr[k + 0], yv[k + 0], d0);
            d1 = fmaf(wr[k + 1], yv[k + 1], d1);
            d2 = fmaf(wr[k + 2], yv[k + 2], d2);
            d3 = fmaf(wr[k + 3], yv[k + 3], d3);
        }
        float tt = fmaf((d0 + d1) + (d2 + d3), s4[o0 + o], b4[o0 + o]);
        out[base + (size_t)o * kN] = silu(tt) + x[base + (size_t)o * kN];
    }
}

// ---------------------------------------------------------------------------
extern "C" void kernel_launch(void* const* d_in, const int* in_sizes, int n_in,
                              void* d_out, int out_size, void* d_ws, size_t ws_size,
                              hipStream_t stream)
{
    (void)in_sizes; (void)n_in; (void)out_size; (void)ws_size;
    const float* x  = (const float*)d_in[0];
    const float* w1 = (const float*)d_in[1];
    const float* s1 = (const float*)d_in[2];
    const float* b1 = (const float*)d_in[3];
    const float* w2 = (const float*)d_in[4];
    const float* s2 = (const float*)d_in[5];
    const float* b2 = (const float*)d_in[6];
    const float* w3 = (const float*)d_in[7];
    const float* s3 = (const float*)d_in[8];
    const float* b3 = (const float*)d_in[9];
    const float* w4 = (const float*)d_in[10];
    const float* s4 = (const float*)d_in[11];
    const float* b4 = (const float*)d_in[12];
    float* out = (float*)d_out;

    unsigned char* ws = (unsigned char*)d_ws;
    size_t off = 0;
    unsigned short* y1t = (unsigned short*)(ws + off); off += (size_t)kRowsT * kCi * 2;
    unsigned short* y2t = (unsigned short*)(ws + off); off += (size_t)kRowsT * kCi * 2;
    unsigned short* y3t = (unsigned short*)(ws + off); off += (size_t)kRowsT * kCi * 2;
    unsigned short* v3T = (unsigned short*)(ws + off); off += (size_t)kRowsT * kCi * 2;
    float*          ylt = (float*)(ws + off);          off += (size_t)kRowsT * kCi * 4;

    k1_proj<<<dim3(kRowsT / 64), dim3(256), 0, stream>>>(
        x, w1, s1, b1, w2, s2, b2, w3, s3, b3, y1t, y2t, y3t);
    kA_stats<<<dim3(kBt * (kN / 64)), dim3(256), 0, stream>>>(y1t, y2t, y3t, v3T);
    kB_pv<<<dim3(kBt * (kN / 64)), dim3(256), 0, stream>>>(y1t, y2t, v3T, ylt);
    k4_out<<<dim3(kRowsT / 256, kC / 32), dim3(256), 0, stream>>>(
        ylt, w4, s4, b4, x, out);
}

// Round 3
// 253.997 us; speedup vs baseline: 2.9112x; 1.3395x over previous
//
#include <hip/hip_runtime.h>
#include <hip/hip_bf16.h>
#include <cstddef>
#include <cstdint>

// NonLocal block, MI355X. Round 3: ALL matmuls on MFMA.
//   k0_pack: weights (BN scale folded) -> A-fragment order, bf16.
//   k1_mfma: 3 projections, B-frag gathered straight from global f32 x.
//   kA/kB:   attention (unchanged from round 2, validated).
//   k4_mfma: final conv + SiLU + residual, K=32 = single MFMA step.

namespace {
constexpr int kBt  = 8;
constexpr int kC   = 256;
constexpr int kCi  = 32;
constexpr int kN   = 4096;           // H*W
constexpr int kRowsT = kBt * kN;     // 32768
constexpr float kLog2e = 1.4426950408889634f;

typedef __attribute__((ext_vector_type(8))) short short8;
typedef __attribute__((ext_vector_type(4))) float f32x4;
}

__device__ __forceinline__ float fast_exp2(float x) { return __builtin_amdgcn_exp2f(x); }
__device__ __forceinline__ float fast_rcp(float x)  { return __builtin_amdgcn_rcpf(x); }
__device__ __forceinline__ float silu(float t) {
    return t * fast_rcp(1.f + fast_exp2(-t * kLog2e));
}
__device__ __forceinline__ unsigned short f2bf(float f) {
    union { float f; uint32_t u; } v; v.f = f;
    return (unsigned short)((v.u + 0x7FFFu + ((v.u >> 16) & 1u)) >> 16);
}
__device__ __forceinline__ float bf2f(unsigned short u) {
    union { uint32_t u; float f; } v; v.u = ((uint32_t)u) << 16;
    return v.f;
}

// ---------------------------------------------------------------------------
// K0: pack weights into MFMA A-fragment order (scale folded in).
// wfA[ot*8+kt][lane] : proj weights, ot in 0..5 (pairs per proj), kt in 0..7.
// w4f[ot][lane]      : w4, 16 ot tiles, K=32 (single kt).
// A-frag (16x16x32): lane l -> row = l&15, k = 8*(l>>4)+e.
// ---------------------------------------------------------------------------
__global__ __launch_bounds__(64) void k0_pack(
    const float* __restrict__ w1, const float* __restrict__ s1,
    const float* __restrict__ w2, const float* __restrict__ s2,
    const float* __restrict__ w3, const float* __restrict__ s3,
    const float* __restrict__ w4, const float* __restrict__ s4,
    short8* __restrict__ wfA, short8* __restrict__ w4f)
{
    const int l = threadIdx.x;
    const int bid = blockIdx.x;
    short8 v;
    if (bid < 48) {
        int ot = bid >> 3, kt = bid & 7;
        int p  = ot >> 1;
        int ocp = (ot & 1) * 16 + (l & 15);
        int k0  = kt * 32 + (l >> 4) * 8;
        const float* wp = (p == 0) ? w1 : (p == 1) ? w2 : w3;
        const float* sp = (p == 0) ? s1 : (p == 1) ? s2 : s3;
        float s = sp[ocp];
        #pragma unroll
        for (int e = 0; e < 8; ++e)
            v[e] = (short)f2bf(wp[ocp * kC + k0 + e] * s);
        wfA[bid * 64 + l] = v;
    } else {
        int ot = bid - 48;
        int oc = ot * 16 + (l & 15);
        int k0 = (l >> 4) * 8;
        float s = s4[oc];
        #pragma unroll
        for (int e = 0; e < 8; ++e)
            v[e] = (short)f2bf(w4[oc * kCi + k0 + e] * s);
        w4f[ot * 64 + l] = v;
    }
}

// ---------------------------------------------------------------------------
// K1: projections via MFMA. Block = 4 waves = 64 px; wave owns 16 px.
// B-frag gathered from global f32 x (8 strided loads per kt; each 16-lane
// group reads 64B-contiguous, every x byte fetched exactly once).
// D: col = l&15 = px, row = 4*(l>>4)+j = out-ch local.
// ---------------------------------------------------------------------------
__global__ __launch_bounds__(256) void k1_mfma(
    const float* __restrict__ x, const short8* __restrict__ wfA,
    const float* __restrict__ b1, const float* __restrict__ b2,
    const float* __restrict__ b3,
    unsigned short* __restrict__ y1t, unsigned short* __restrict__ y2t,
    unsigned short* __restrict__ y3t)
{
    const int l  = threadIdx.x & 63;
    const int w  = threadIdx.x >> 6;
    const int b  = blockIdx.x >> 6;
    const int n0 = (blockIdx.x & 63) * 64 + w * 16;
    const int px = l & 15, g = l >> 4;

    const float* xb = x + (size_t)b * kC * kN + n0 + px;

    f32x4 acc[6];
    #pragma unroll
    for (int ot = 0; ot < 6; ++ot) acc[ot] = (f32x4){0.f, 0.f, 0.f, 0.f};

    #pragma unroll
    for (int kt = 0; kt < 8; ++kt) {
        const float* xc = xb + (size_t)(kt * 32 + g * 8) * kN;
        float f[8];
        #pragma unroll
        for (int e = 0; e < 8; ++e) f[e] = xc[(size_t)e * kN];
        short8 Bf;
        #pragma unroll
        for (int e = 0; e < 8; ++e) Bf[e] = (short)f2bf(f[e]);
        #pragma unroll
        for (int ot = 0; ot < 6; ++ot)
            acc[ot] = __builtin_amdgcn_mfma_f32_16x16x32_bf16(
                wfA[(ot * 8 + kt) * 64 + l], Bf, acc[ot], 0, 0, 0);
    }

    const size_t rowbase = ((size_t)(b * kN) + n0 + px) * kCi;
    #pragma unroll
    for (int pp = 0; pp < 3; ++pp) {
        const float* bp = (pp == 0) ? b1 : (pp == 1) ? b2 : b3;
        unsigned short* yp = (pp == 0) ? y1t : (pp == 1) ? y2t : y3t;
        const float mul = (pp == 1) ? kLog2e : 1.0f;
        #pragma unroll
        for (int h = 0; h < 2; ++h) {
            int ot = pp * 2 + h;
            int oc0 = h * 16 + 4 * g;
            unsigned int wd[2];
            #pragma unroll
            for (int j2 = 0; j2 < 2; ++j2) {
                float v0 = silu(acc[ot][2 * j2]     + bp[oc0 + 2 * j2])     * mul;
                float v1 = silu(acc[ot][2 * j2 + 1] + bp[oc0 + 2 * j2 + 1]) * mul;
                wd[j2] = (unsigned)f2bf(v0) | ((unsigned)f2bf(v1) << 16);
            }
            *(uint2*)(yp + rowbase + oc0) = make_uint2(wd[0], wd[1]);
        }
    }
}

// ---------------------------------------------------------------------------
// KA: softmax denominators via MFMA, then v3T[b][c][n] = y3[n][c]/sumexp[n].
// ---------------------------------------------------------------------------
__global__ __launch_bounds__(256) void kA_stats(
    const unsigned short* __restrict__ y1t, const unsigned short* __restrict__ y2t,
    const unsigned short* __restrict__ y3t, unsigned short* __restrict__ v3T)
{
    const int l   = threadIdx.x & 63;
    const int w   = __builtin_amdgcn_readfirstlane(threadIdx.x >> 6);
    const int b   = blockIdx.x >> 6;
    const int n0  = (blockIdx.x & 63) * 64;
    const int r16 = l & 15, g = l >> 4;

    const short8 Af = *(const short8*)(
        y2t + ((size_t)(b * kN + n0 + w * 16 + r16) * kCi + g * 8));
    const unsigned short* y1b = y1t + (size_t)b * kN * kCi + (size_t)r16 * kCi + g * 8;

    float s0 = 0.f, s1 = 0.f, s2 = 0.f, s3 = 0.f;
    #pragma unroll 4
    for (int mt = 0; mt < kN / 16; ++mt) {
        short8 Bf = *(const short8*)(y1b + (size_t)mt * 16 * kCi);
        f32x4 z = {0.f, 0.f, 0.f, 0.f};
        f32x4 S = __builtin_amdgcn_mfma_f32_16x16x32_bf16(Af, Bf, z, 0, 0, 0);
        s0 += fast_exp2(S[0]);
        s1 += fast_exp2(S[1]);
        s2 += fast_exp2(S[2]);
        s3 += fast_exp2(S[3]);
    }
    #pragma unroll
    for (int d = 1; d < 16; d <<= 1) {
        s0 += __shfl_xor(s0, d);
        s1 += __shfl_xor(s1, d);
        s2 += __shfl_xor(s2, d);
        s3 += __shfl_xor(s3, d);
    }
    __shared__ float ssum[64];
    if (r16 == 0) {
        ssum[w * 16 + g * 4 + 0] = s0;
        ssum[w * 16 + g * 4 + 1] = s1;
        ssum[w * 16 + g * 4 + 2] = s2;
        ssum[w * 16 + g * 4 + 3] = s3;
    }
    __syncthreads();

    const int t = threadIdx.x;
    const int c = t >> 3, q = t & 7;
    float rin[8];
    #pragma unroll
    for (int u = 0; u < 8; ++u) rin[u] = fast_rcp(ssum[q * 8 + u]);
    unsigned int wds[4];
    #pragma unroll
    for (int u = 0; u < 4; ++u) {
        float a0 = bf2f(y3t[(size_t)(b * kN + n0 + q * 8 + 2 * u) * kCi + c]) * rin[2 * u];
        float a1 = bf2f(y3t[(size_t)(b * kN + n0 + q * 8 + 2 * u + 1) * kCi + c]) * rin[2 * u + 1];
        wds[u] = (unsigned)f2bf(a0) | ((unsigned)f2bf(a1) << 16);
    }
    uint4 pack = make_uint4(wds[0], wds[1], wds[2], wds[3]);
    *(uint4*)(v3T + ((size_t)(b * kCi + c) * kN + n0 + q * 8)) = pack;
}

// ---------------------------------------------------------------------------
// KB: out[m][c] = sum_n 2^S[n,m] * v3[n][c]; output now bf16 [m][32].
// ---------------------------------------------------------------------------
__global__ __launch_bounds__(256) void kB_pv(
    const unsigned short* __restrict__ y1t, const unsigned short* __restrict__ y2t,
    const unsigned short* __restrict__ v3T, unsigned short* __restrict__ yltb)
{
    __shared__ unsigned int plds[4][20 * 16];   // per-wave P tile, 80B row stride
    const int l   = threadIdx.x & 63;
    const int w   = __builtin_amdgcn_readfirstlane(threadIdx.x >> 6);
    const int b   = blockIdx.x >> 6;
    const int m0  = (blockIdx.x & 63) * 64 + w * 16;
    const int r16 = l & 15, g = l >> 4;

    const short8 B1 = *(const short8*)(
        y1t + ((size_t)(b * kN + m0 + r16) * kCi + g * 8));
    const unsigned short* y2b = y2t + (size_t)b * kN * kCi + (size_t)r16 * kCi + g * 8;
    const unsigned short* v3b = v3T + (size_t)b * kCi * kN + (size_t)r16 * kN + g * 8;

    f32x4 acc0 = {0.f, 0.f, 0.f, 0.f};
    f32x4 acc1 = {0.f, 0.f, 0.f, 0.f};
    unsigned int* pw = &plds[w][r16 * 20];

    #pragma unroll 2
    for (int nt = 0; nt < kN / 32; ++nt) {
        const size_t nb = (size_t)nt * 32;
        short8 A2a = *(const short8*)(y2b + nb * kCi);
        short8 A2b = *(const short8*)(y2b + (nb + 16) * kCi);
        f32x4 z = {0.f, 0.f, 0.f, 0.f};
        f32x4 S0 = __builtin_amdgcn_mfma_f32_16x16x32_bf16(A2a, B1, z, 0, 0, 0);
        f32x4 S1 = __builtin_amdgcn_mfma_f32_16x16x32_bf16(A2b, B1, z, 0, 0, 0);

        float p0 = fast_exp2(S0[0]), p1 = fast_exp2(S0[1]);
        float p2 = fast_exp2(S0[2]), p3 = fast_exp2(S0[3]);
        float p4 = fast_exp2(S1[0]), p5 = fast_exp2(S1[1]);
        float p6 = fast_exp2(S1[2]), p7 = fast_exp2(S1[3]);

        uint2 w01, w23;
        w01.x = (unsigned)f2bf(p0) | ((unsigned)f2bf(p1) << 16);
        w01.y = (unsigned)f2bf(p2) | ((unsigned)f2bf(p3) << 16);
        w23.x = (unsigned)f2bf(p4) | ((unsigned)f2bf(p5) << 16);
        w23.y = (unsigned)f2bf(p6) | ((unsigned)f2bf(p7) << 16);
        *(uint2*)(pw + 2 * g)     = w01;
        *(uint2*)(pw + 8 + 2 * g) = w23;

        short8 A3a = *(const short8*)(v3b + nb);
        short8 A3b = *(const short8*)(v3b + 16 * (size_t)kN + nb);

        asm volatile("" ::: "memory");
        short8 Bp = *(const short8*)(&plds[w][r16 * 20 + 4 * g]);

        acc0 = __builtin_amdgcn_mfma_f32_16x16x32_bf16(A3a, Bp, acc0, 0, 0, 0);
        acc1 = __builtin_amdgcn_mfma_f32_16x16x32_bf16(A3b, Bp, acc1, 0, 0, 0);
    }

    // D: lane -> m = l&15, c = 4g+j (acc0) / 16+4g+j (acc1); pack bf16.
    unsigned short* outp = yltb + ((size_t)(b * kN) + m0 + r16) * kCi;
    uint2 wa, wb;
    wa.x = (unsigned)f2bf(acc0[0]) | ((unsigned)f2bf(acc0[1]) << 16);
    wa.y = (unsigned)f2bf(acc0[2]) | ((unsigned)f2bf(acc0[3]) << 16);
    wb.x = (unsigned)f2bf(acc1[0]) | ((unsigned)f2bf(acc1[1]) << 16);
    wb.y = (unsigned)f2bf(acc1[2]) | ((unsigned)f2bf(acc1[3]) << 16);
    *(uint2*)(outp + 4 * g)      = wa;
    *(uint2*)(outp + 16 + 4 * g) = wb;
}

// ---------------------------------------------------------------------------
// K4: final conv (32->256) via MFMA (K=32 = one step) + SiLU + residual.
// Block = 4 waves = 64 px; wave: 1 B-frag from bf16 ylt, 16 MFMAs.
// ---------------------------------------------------------------------------
__global__ __launch_bounds__(256) void k4_mfma(
    const unsigned short* __restrict__ ylt, const short8* __restrict__ w4f,
    const float* __restrict__ b4, const float* __restrict__ x,
    float* __restrict__ out)
{
    const int l  = threadIdx.x & 63;
    const int w  = threadIdx.x >> 6;
    const int b  = blockIdx.x >> 6;
    const int n0 = (blockIdx.x & 63) * 64 + w * 16;
    const int px = l & 15, g = l >> 4;

    const short8 Bf = *(const short8*)(
        ylt + ((size_t)(b * kN) + n0 + px) * kCi + g * 8);

    f32x4 acc[16];
    #pragma unroll
    for (int ot = 0; ot < 16; ++ot) {
        f32x4 z = {0.f, 0.f, 0.f, 0.f};
        acc[ot] = __builtin_amdgcn_mfma_f32_16x16x32_bf16(
            w4f[ot * 64 + l], Bf, z, 0, 0, 0);
    }

    const size_t pxg = (size_t)b * kC * kN + n0 + px;   // + oc*kN
    #pragma unroll
    for (int ot = 0; ot < 16; ++ot) {
        const int oc0 = ot * 16 + 4 * g;
        float4 bb = *(const float4*)(b4 + oc0);
        const float bbv[4] = {bb.x, bb.y, bb.z, bb.w};
        #pragma unroll
        for (int j = 0; j < 4; ++j) {
            const size_t idx = pxg + (size_t)(oc0 + j) * kN;
            float t = acc[ot][j] + bbv[j];
            out[idx] = silu(t) + x[idx];
        }
    }
}

// ---------------------------------------------------------------------------
extern "C" void kernel_launch(void* const* d_in, const int* in_sizes, int n_in,
                              void* d_out, int out_size, void* d_ws, size_t ws_size,
                              hipStream_t stream)
{
    (void)in_sizes; (void)n_in; (void)out_size; (void)ws_size;
    const float* x  = (const float*)d_in[0];
    const float* w1 = (const float*)d_in[1];
    const float* s1 = (const float*)d_in[2];
    const float* b1 = (const float*)d_in[3];
    const float* w2 = (const float*)d_in[4];
    const float* s2 = (const float*)d_in[5];
    const float* b2 = (const float*)d_in[6];
    const float* w3 = (const float*)d_in[7];
    const float* s3 = (const float*)d_in[8];
    const float* b3 = (const float*)d_in[9];
    const float* w4 = (const float*)d_in[10];
    const float* s4 = (const float*)d_in[11];
    const float* b4 = (const float*)d_in[12];
    float* out = (float*)d_out;

    unsigned char* ws = (unsigned char*)d_ws;
    size_t off = 0;
    unsigned short* y1t = (unsigned short*)(ws + off); off += (size_t)kRowsT * kCi * 2;
    unsigned short* y2t = (unsigned short*)(ws + off); off += (size_t)kRowsT * kCi * 2;
    unsigned short* y3t = (unsigned short*)(ws + off); off += (size_t)kRowsT * kCi * 2;
    unsigned short* v3T = (unsigned short*)(ws + off); off += (size_t)kRowsT * kCi * 2;
    unsigned short* yltb= (unsigned short*)(ws + off); off += (size_t)kRowsT * kCi * 2;
    short8* wfA = (short8*)(ws + off); off += 48 * 64 * sizeof(short8);
    short8* w4f = (short8*)(ws + off); off += 16 * 64 * sizeof(short8);

    k0_pack<<<dim3(64), dim3(64), 0, stream>>>(
        w1, s1, w2, s2, w3, s3, w4, s4, wfA, w4f);
    k1_mfma<<<dim3(kRowsT / 64), dim3(256), 0, stream>>>(
        x, wfA, b1, b2, b3, y1t, y2t, y3t);
    kA_stats<<<dim3(kBt * (kN / 64)), dim3(256), 0, stream>>>(y1t, y2t, y3t, v3T);
    kB_pv<<<dim3(kBt * (kN / 64)), dim3(256), 0, stream>>>(y1t, y2t, v3T, yltb);
    k4_mfma<<<dim3(kRowsT / 64), dim3(256), 0, stream>>>(
        yltb, w4f, b4, x, out);
}